// Round 3
// baseline (27.851 us; speedup 1.0000x reference)
//
#include <hip/hip_runtime.h>

#define NPTS 8192
#define THREADS 256
#define PPT 8                   // points per thread
#define PPB (THREADS * PPT)     // 2048 points per block
#define PBLKS (NPTS / PPB)      // 4 point-blocks
#define NCHUNK 32               // candidate chunks
#define CAND (NPTS / NCHUNK)    // 256 candidates per chunk
#define WSROW (6 * NPTS)        // floats per chunk-slice: 49152
#define REDBLKS 48              // 49152/1024 slices for stage-1 reduce

// Kernel 1: per (channel, direction, point-block, candidate-chunk) block,
// compute partial min |x - c| over this chunk's candidates and store to a
// chunk-private ws slice (no atomics, no init needed - every slot written).
__global__ __launch_bounds__(THREADS) void chamfer_min_kernel(
    const float* __restrict__ pred, const float* __restrict__ target,
    float* __restrict__ ws)
{
    int b = blockIdx.x;
    const int ck  = b & (NCHUNK - 1); b >>= 5;
    const int pb  = b & (PBLKS - 1);  b >>= 2;
    const int dir = b & 1;            b >>= 1;
    const int ch  = b;                // 0..2

    const float* pts  = dir ? target : pred;   // dir=0: pred->target
    const float* cnds = dir ? pred   : target;

    __shared__ float s[CAND];
    const int t = threadIdx.x;
    for (int k = t; k < CAND; k += THREADS)
        s[k] = cnds[(ck * CAND + k) * 3 + ch];

    float x[PPT], m[PPT];
    #pragma unroll
    for (int p = 0; p < PPT; ++p) {
        x[p] = pts[(pb * PPB + p * THREADS + t) * 3 + ch];
        m[p] = 3.0e38f;
    }
    __syncthreads();

    // Pairs of candidates: 1 ds_read_b64 + PPT*3 VALU (sub, sub, v_min3 with
    // abs modifiers) per iteration -> 1.5 VALU/pair.
    #pragma unroll 4
    for (int k2 = 0; k2 < CAND / 2; ++k2) {
        const float2 c = ((const float2*)s)[k2];
        #pragma unroll
        for (int p = 0; p < PPT; ++p) {
            const float d0 = x[p] - c.x;
            const float d1 = x[p] - c.y;
            m[p] = fminf(m[p], fminf(fabsf(d0), fabsf(d1)));
        }
    }

    float* w = ws + (size_t)ck * WSROW + (ch * 2 + dir) * NPTS + pb * PPB;
    #pragma unroll
    for (int p = 0; p < PPT; ++p)
        w[p * THREADS + t] = m[p];
}

// Stage 1 reduce: 48 blocks; each covers 1024 points, min over the 32 chunk
// slices (float4 coalesced), then sums its 1024 per-point mins -> 1 partial.
__global__ __launch_bounds__(THREADS) void chamfer_red1_kernel(
    const float* __restrict__ ws, float* __restrict__ partials)
{
    const int t = threadIdx.x;
    const size_t base = (size_t)blockIdx.x * 1024;

    float4 m = make_float4(3.0e38f, 3.0e38f, 3.0e38f, 3.0e38f);
    #pragma unroll 4
    for (int ck = 0; ck < NCHUNK; ++ck) {
        const float4 v = ((const float4*)(ws + (size_t)ck * WSROW + base))[t];
        m.x = fminf(m.x, v.x); m.y = fminf(m.y, v.y);
        m.z = fminf(m.z, v.z); m.w = fminf(m.w, v.w);
    }
    float sum = (m.x + m.y) + (m.z + m.w);

    #pragma unroll
    for (int off = 32; off > 0; off >>= 1)
        sum += __shfl_down(sum, off, 64);

    __shared__ float wsum[THREADS / 64];
    if ((t & 63) == 0) wsum[t >> 6] = sum;
    __syncthreads();
    if (t == 0) {
        float tot = 0.f;
        #pragma unroll
        for (int w = 0; w < THREADS / 64; ++w) tot += wsum[w];
        partials[blockIdx.x] = tot;
    }
}

// Stage 2 reduce: one wave sums the 48 partials and scales by 1/NPTS.
__global__ __launch_bounds__(64) void chamfer_red2_kernel(
    const float* __restrict__ partials, float* __restrict__ out)
{
    const int t = threadIdx.x;
    float sum = (t < REDBLKS) ? partials[t] : 0.f;
    #pragma unroll
    for (int off = 32; off > 0; off >>= 1)
        sum += __shfl_down(sum, off, 64);
    if (t == 0) out[0] = sum * (1.0f / NPTS);
}

extern "C" void kernel_launch(void* const* d_in, const int* in_sizes, int n_in,
                              void* d_out, int out_size, void* d_ws, size_t ws_size,
                              hipStream_t stream) {
    const float* pred   = (const float*)d_in[0];
    const float* target = (const float*)d_in[1];
    float* out = (float*)d_out;
    float* ws = (float*)d_ws;                               // [NCHUNK][6][NPTS]
    float* partials = ws + (size_t)NCHUNK * WSROW;          // [REDBLKS]

    chamfer_min_kernel<<<3 * 2 * PBLKS * NCHUNK, THREADS, 0, stream>>>(pred, target, ws);
    chamfer_red1_kernel<<<REDBLKS, THREADS, 0, stream>>>(ws, partials);
    chamfer_red2_kernel<<<1, 64, 0, stream>>>(partials, out);
}